// Round 6
// baseline (1425.669 us; speedup 1.0000x reference)
//
#include <hip/hip_runtime.h>

// SlidingWindowAttention: S=512, L=2048, WINDOW=64, STRIDE=32 -> NW=63, E=64, H=8, HD=8
// f32 in/out. Rounds 3-5: ~600MB symmetric HBM excess == per-thread arrays
// (accw/kb/sc/p) never promoted out of allocas (SROA sees variable GEPs
// before unrolling) -> every accumulate was a scratch round-trip; VGPR=64
// proves demand stayed low because state lived in memory. This round: ZERO
// local arrays — all state is named scalars / ext_vector SSA values with
// literal subscripts via macro expansion. Scratch is impossible by construction.
#define S_DIM 512
#define L_DIM 2048
#define NW 63
#define E_DIM 64
#define NH 8
#define HD 8

typedef __bf16 bf16_t;
typedef __bf16 bf16x8 __attribute__((ext_vector_type(8)));
typedef float f32x4 __attribute__((ext_vector_type(4)));
typedef float f32x8 __attribute__((ext_vector_type(8)));

// 8 consecutive f32 -> bf16x8 MFMA fragment (RNE converts)
__device__ inline bf16x8 cvt8(const float* __restrict__ p) {
    float4 a = *(const float4*)p;
    float4 b = *(const float4*)(p + 4);
    bf16x8 r;
    r[0] = (bf16_t)a.x; r[1] = (bf16_t)a.y; r[2] = (bf16_t)a.z; r[3] = (bf16_t)a.w;
    r[4] = (bf16_t)b.x; r[5] = (bf16_t)b.y; r[6] = (bf16_t)b.z; r[7] = (bf16_t)b.w;
    return r;
}

// dot(q[0:8], kbJ[0:8]) — all-literal indices
#define DOT8(Q0, Q1, KB) \
    fmaf((Q1)[3], (float)(KB)[7], fmaf((Q1)[2], (float)(KB)[6], \
    fmaf((Q1)[1], (float)(KB)[5], fmaf((Q1)[0], (float)(KB)[4], \
    fmaf((Q0)[3], (float)(KB)[3], fmaf((Q0)[2], (float)(KB)[2], \
    fmaf((Q0)[1], (float)(KB)[1], (Q0)[0] * (float)(KB)[0])))))))

// p0..p7 += A * vb[0..7] — all-literal indices
#define CTXJ(A, VB) {                                                         \
    p0 = fmaf(A, (float)(VB)[0], p0); p1 = fmaf(A, (float)(VB)[1], p1);       \
    p2 = fmaf(A, (float)(VB)[2], p2); p3 = fmaf(A, (float)(VB)[3], p3);       \
    p4 = fmaf(A, (float)(VB)[4], p4); p5 = fmaf(A, (float)(VB)[5], p5);       \
    p6 = fmaf(A, (float)(VB)[6], p6); p7 = fmaf(A, (float)(VB)[7], p7); }

// One Q-row: scores -> softmax -> attn-mean accum -> ctx -> transpose-reduce.
// R is a literal (0..3); accw##R is an f32x8 SSA vector.
#define ROWBODY(R) {                                                          \
    int row = wave * 4 + R;                                                   \
    f32x4 q0 = *(const f32x4*)(&qp_s[row][h * 8]);                            \
    f32x4 q1 = *(const f32x4*)(&qp_s[row][h * 8 + 4]);                        \
    float s0 = DOT8(q0, q1, kb0), s1 = DOT8(q0, q1, kb1);                     \
    float s2 = DOT8(q0, q1, kb2), s3 = DOT8(q0, q1, kb3);                     \
    float s4 = DOT8(q0, q1, kb4), s5 = DOT8(q0, q1, kb5);                     \
    float s6 = DOT8(q0, q1, kb6), s7 = DOT8(q0, q1, kb7);                     \
    float mx = fmaxf(fmaxf(fmaxf(s0, s1), fmaxf(s2, s3)),                     \
                     fmaxf(fmaxf(s4, s5), fmaxf(s6, s7)));                    \
    mx = fmaxf(mx, __shfl_xor(mx, 1, 64));                                    \
    mx = fmaxf(mx, __shfl_xor(mx, 2, 64));                                    \
    mx = fmaxf(mx, __shfl_xor(mx, 4, 64));                                    \
    mx = fmaxf(mx, __shfl_xor(mx, 8, 64));                                    \
    mx = fmaxf(mx, __shfl_xor(mx, 16, 64));                                   \
    mx = fmaxf(mx, __shfl_xor(mx, 32, 64));                                   \
    s0 = exp2f(s0 - mx); s1 = exp2f(s1 - mx); s2 = exp2f(s2 - mx);            \
    s3 = exp2f(s3 - mx); s4 = exp2f(s4 - mx); s5 = exp2f(s5 - mx);            \
    s6 = exp2f(s6 - mx); s7 = exp2f(s7 - mx);                                 \
    float l = ((s0 + s1) + (s2 + s3)) + ((s4 + s5) + (s6 + s7));              \
    l += __shfl_xor(l, 1, 64);  l += __shfl_xor(l, 2, 64);                    \
    l += __shfl_xor(l, 4, 64);  l += __shfl_xor(l, 8, 64);                    \
    l += __shfl_xor(l, 16, 64); l += __shfl_xor(l, 32, 64);                   \
    float inv = 1.0f / l;                                                     \
    s0 *= inv; s1 *= inv; s2 *= inv; s3 *= inv;                               \
    s4 *= inv; s5 *= inv; s6 *= inv; s7 *= inv;                               \
    accw##R = accw##R + (f32x8){s0, s1, s2, s3, s4, s5, s6, s7} * 0.125f;     \
    float p0 = 0.f, p1 = 0.f, p2 = 0.f, p3 = 0.f;                             \
    float p4 = 0.f, p5 = 0.f, p6 = 0.f, p7 = 0.f;                             \
    { bf16x8 vb = *(const bf16x8*)(&vp_s[lane      ][h01 * 8]); CTXJ(s0, vb); } \
    { bf16x8 vb = *(const bf16x8*)(&vp_s[lane +  64][h01 * 8]); CTXJ(s1, vb); } \
    { bf16x8 vb = *(const bf16x8*)(&vp_s[lane + 128][h01 * 8]); CTXJ(s2, vb); } \
    { bf16x8 vb = *(const bf16x8*)(&vp_s[lane + 192][h01 * 8]); CTXJ(s3, vb); } \
    { bf16x8 vb = *(const bf16x8*)(&vp_s[lane + 256][h01 * 8]); CTXJ(s4, vb); } \
    { bf16x8 vb = *(const bf16x8*)(&vp_s[lane + 320][h01 * 8]); CTXJ(s5, vb); } \
    { bf16x8 vb = *(const bf16x8*)(&vp_s[lane + 384][h01 * 8]); CTXJ(s6, vb); } \
    { bf16x8 vb = *(const bf16x8*)(&vp_s[lane + 448][h01 * 8]); CTXJ(s7, vb); } \
    int u1 = lane & 1, u2 = lane & 2, u4 = lane & 4;                          \
    float a0 = (u1 ? p1 : p0) + __shfl_xor(u1 ? p0 : p1, 1, 64);              \
    float a1 = (u1 ? p3 : p2) + __shfl_xor(u1 ? p2 : p3, 1, 64);              \
    float a2 = (u1 ? p5 : p4) + __shfl_xor(u1 ? p4 : p5, 1, 64);              \
    float a3 = (u1 ? p7 : p6) + __shfl_xor(u1 ? p6 : p7, 1, 64);              \
    float b0 = (u2 ? a1 : a0) + __shfl_xor(u2 ? a0 : a1, 2, 64);              \
    float b1 = (u2 ? a3 : a2) + __shfl_xor(u2 ? a2 : a3, 2, 64);              \
    float c0 = (u4 ? b1 : b0) + __shfl_xor(u4 ? b0 : b1, 4, 64);              \
    c0 += __shfl_xor(c0, 8, 64);                                              \
    c0 += __shfl_xor(c0, 16, 64);                                             \
    c0 += __shfl_xor(c0, 32, 64);                                             \
    if (lane < 8) ctx_s[row][h * 8 + lane] = c0; }

#define STORE_AW(R) {                                                         \
    int s = srow0 + wave * 4 + R;                                             \
    float* dst = out_aw + ((size_t)(n * S_DIM + s)) * S_DIM + lane;           \
    dst[0]   = accw##R[0]; dst[64]  = accw##R[1];                             \
    dst[128] = accw##R[2]; dst[192] = accw##R[3];                             \
    dst[256] = accw##R[4]; dst[320] = accw##R[5];                             \
    dst[384] = accw##R[6]; dst[448] = accw##R[7]; }

__global__ __launch_bounds__(512, 4) void swa_fused(
    const float* __restrict__ q, const float* __restrict__ k,
    const float* __restrict__ v, const float* __restrict__ w,
    const float* __restrict__ bias, const float* __restrict__ wout,
    const float* __restrict__ bout, float* __restrict__ out)
{
    // kp_s/vp_s: [512][16] head-pair projections (bf16), padded to 24
    // (48B row stride: 16B-aligned for ds_read_b128).
    __shared__ __align__(16) bf16_t kp_s[S_DIM][24];
    __shared__ __align__(16) bf16_t vp_s[S_DIM][24];
    __shared__ __align__(16) float  qp_s[32][64];   // this tile's scaled qp, f32
    __shared__ float  ctx_s[32][68];
    __shared__ bf16_t wo_t[64][66];                 // wo transposed: [f][e]
    __shared__ float  bo_s[64];

    int tid  = threadIdx.x;
    int lane = tid & 63, wave = tid >> 6;    // 8 waves
    int bid  = blockIdx.x;
    int n    = bid >> 4;             // 63 windows x 16 row-tiles
    int tile = bid & 15;
    int srow0 = tile * 32;

    float* out_x  = out;
    float* out_aw = out + (size_t)S_DIM * NW * E_DIM;

    // ---- stage out-proj (transposed) + bias; first hp barrier orders these ----
#pragma unroll
    for (int i = 0; i < 8; ++i) {
        int idx = tid + i * 512;                    // idx = e*64 + f
        wo_t[idx & 63][idx >> 6] = (bf16_t)wout[idx];
    }
    if (tid < 64) bo_s[tid] = bout[tid];

    int ml = lane & 15, quad = lane >> 4;

    // ---- qp for this block's 32 rows via MFMA (waves 0,1), scale*log2e folded ----
    if (wave < 2) {
        int s0 = srow0 + wave * 16;
        float bq0 = bias[ml],      bq1 = bias[16 + ml];
        float bq2 = bias[32 + ml], bq3 = bias[48 + ml];
        f32x4 acc0 = (f32x4){bq0, bq0, bq0, bq0};
        f32x4 acc1 = (f32x4){bq1, bq1, bq1, bq1};
        f32x4 acc2 = (f32x4){bq2, bq2, bq2, bq2};
        f32x4 acc3 = (f32x4){bq3, bq3, bq3, bq3};
        int arow = (s0 + ml) * L_DIM + 32 * n + quad * 8;
#pragma unroll
        for (int k0 = 0; k0 < 64; k0 += 32) {
            bf16x8 afrag = cvt8(q + arow + k0);
            bf16x8 bf0 = cvt8(w + (ml)      * 64 + k0 + quad * 8);
            bf16x8 bf1 = cvt8(w + (16 + ml) * 64 + k0 + quad * 8);
            bf16x8 bf2 = cvt8(w + (32 + ml) * 64 + k0 + quad * 8);
            bf16x8 bf3 = cvt8(w + (48 + ml) * 64 + k0 + quad * 8);
            acc0 = __builtin_amdgcn_mfma_f32_16x16x32_bf16(afrag, bf0, acc0, 0, 0, 0);
            acc1 = __builtin_amdgcn_mfma_f32_16x16x32_bf16(afrag, bf1, acc1, 0, 0, 0);
            acc2 = __builtin_amdgcn_mfma_f32_16x16x32_bf16(afrag, bf2, acc2, 0, 0, 0);
            acc3 = __builtin_amdgcn_mfma_f32_16x16x32_bf16(afrag, bf3, acc3, 0, 0, 0);
        }
        const float cs = 0.35355339059327373f * 1.4426950408889634f;
#pragma unroll
        for (int rr = 0; rr < 4; ++rr) {
            qp_s[16 * wave + quad * 4 + rr][ml]      = acc0[rr] * cs;
            qp_s[16 * wave + quad * 4 + rr][16 + ml] = acc1[rr] * cs;
            qp_s[16 * wave + quad * 4 + rr][32 + ml] = acc2[rr] * cs;
            qp_s[16 * wave + quad * 4 + rr][48 + ml] = acc3[rr] * cs;
        }
    }

    // attn-mean accumulators: SSA vectors (never allocas)
    f32x8 accw0 = {0.f, 0.f, 0.f, 0.f, 0.f, 0.f, 0.f, 0.f};
    f32x8 accw1 = accw0, accw2 = accw0, accw3 = accw0;

    for (int hp = 0; hp < 4; ++hp) {
        __syncthreads();   // prev readers done (also orders qp/wo/bo stores at hp=0)

        // ---- stage kp/vp[512][16] for heads {2hp, 2hp+1}: 8 waves x 4 tiles ----
        float bk0 = bias[64 + hp * 16 + ml];
        float bv0 = bias[128 + hp * 16 + ml];
#pragma unroll
        for (int i = 0; i < 4; ++i) {
            int s0 = wave * 64 + 16 * i;
            int arow = (s0 + ml) * L_DIM + 32 * n + quad * 8;
            f32x4 kacc = (f32x4){bk0, bk0, bk0, bk0};
            f32x4 vacc = (f32x4){bv0, bv0, bv0, bv0};
#pragma unroll
            for (int k0 = 0; k0 < 64; k0 += 32) {
                bf16x8 ak = cvt8(k + arow + k0);
                bf16x8 av = cvt8(v + arow + k0);
                bf16x8 bk = cvt8(w + (64 + hp * 16 + ml) * 64 + k0 + quad * 8);
                bf16x8 bv = cvt8(w + (128 + hp * 16 + ml) * 64 + k0 + quad * 8);
                kacc = __builtin_amdgcn_mfma_f32_16x16x32_bf16(ak, bk, kacc, 0, 0, 0);
                vacc = __builtin_amdgcn_mfma_f32_16x16x32_bf16(av, bv, vacc, 0, 0, 0);
            }
#pragma unroll
            for (int rr = 0; rr < 4; ++rr) {
                kp_s[s0 + quad * 4 + rr][ml] = (bf16_t)kacc[rr];
                vp_s[s0 + quad * 4 + rr][ml] = (bf16_t)vacc[rr];
            }
        }
        __syncthreads();

#pragma unroll
        for (int h01 = 0; h01 < 2; ++h01) {
            int h = hp * 2 + h01;

            // K fragments: 8 named SSA vectors (32 VGPRs), lazy cvt at use
            bf16x8 kb0 = *(const bf16x8*)(&kp_s[lane      ][h01 * 8]);
            bf16x8 kb1 = *(const bf16x8*)(&kp_s[lane +  64][h01 * 8]);
            bf16x8 kb2 = *(const bf16x8*)(&kp_s[lane + 128][h01 * 8]);
            bf16x8 kb3 = *(const bf16x8*)(&kp_s[lane + 192][h01 * 8]);
            bf16x8 kb4 = *(const bf16x8*)(&kp_s[lane + 256][h01 * 8]);
            bf16x8 kb5 = *(const bf16x8*)(&kp_s[lane + 320][h01 * 8]);
            bf16x8 kb6 = *(const bf16x8*)(&kp_s[lane + 384][h01 * 8]);
            bf16x8 kb7 = *(const bf16x8*)(&kp_s[lane + 448][h01 * 8]);

            ROWBODY(0) ROWBODY(1) ROWBODY(2) ROWBODY(3)
        }
    }
    __syncthreads();

    // ---- attn_weights [NW][S][S] f32: lanes contiguous in t -> coalesced ----
    STORE_AW(0) STORE_AW(1) STORE_AW(2) STORE_AW(3)

    // ---- out projection: x[s][e] = sum_f ctx[s][f] * Wout[e][f] + bout[e] ----
    int so = tid >> 4;   // 0..31
    int eb = tid & 15;
    float x0 = bo_s[eb], x1 = bo_s[eb + 16], x2 = bo_s[eb + 32], x3 = bo_s[eb + 48];
#pragma unroll
    for (int f = 0; f < 64; ++f) {
        float c = ctx_s[so][f];
        x0 = fmaf(c, (float)wo_t[f][eb],      x0);
        x1 = fmaf(c, (float)wo_t[f][eb + 16], x1);
        x2 = fmaf(c, (float)wo_t[f][eb + 32], x2);
        x3 = fmaf(c, (float)wo_t[f][eb + 48], x3);
    }
    int sg = srow0 + so;
    float* xd = out_x + (size_t)sg * NW * E_DIM + (size_t)n * E_DIM + eb;
    xd[0]  = x0;
    xd[16] = x1;
    xd[32] = x2;
    xd[48] = x3;
}

extern "C" void kernel_launch(void* const* d_in, const int* in_sizes, int n_in,
                              void* d_out, int out_size, void* d_ws, size_t ws_size,
                              hipStream_t stream) {
    const float* q  = (const float*)d_in[0];
    const float* k  = (const float*)d_in[1];
    const float* v  = (const float*)d_in[2];
    const float* w  = (const float*)d_in[3];
    const float* b  = (const float*)d_in[4];
    const float* wo = (const float*)d_in[5];
    const float* bo = (const float*)d_in[6];
    float* out = (float*)d_out;

    // 63 windows * 16 row-tiles = 1008 blocks x 512 threads; no workspace.
    hipLaunchKernelGGL(swa_fused, dim3(NW * 16), dim3(512), 0, stream,
                       q, k, v, w, b, wo, bo, out);
}